// Round 9
// baseline (307.948 us; speedup 1.0000x reference)
//
#include <hip/hip_runtime.h>

#define F 128
#define NN 65536       // node count (layout assumes this, as does COARSE)
#define NBA 512        // D-side binning blocks
#define NBS 128        // S-side binning blocks
#define COARSE 256     // coarse buckets = node >> 8  (assumes N = 65536)
#define CAP_BIN 4864   // slot capacity per bucket, pre-sort (mean 4096, 12 sigma)
#define CAP_CSR 5632   // slot capacity per bucket, post-sort w/ per-row 4-align pads

typedef unsigned int uint;
typedef unsigned short ushort;
typedef unsigned char uchar;
typedef __attribute__((ext_vector_type(8))) short short8;
typedef __attribute__((ext_vector_type(8))) unsigned short ushort8;
typedef __attribute__((ext_vector_type(4))) float floatx4;

__device__ __forceinline__ ushort f2bf(float f) {
  uint u = __float_as_uint(f);
  u += 0x7fffu + ((u >> 16) & 1u);   // round-to-nearest-even
  return (ushort)(u >> 16);
}

// Planar bf16 table layout: element (node n, dim d) lives at
//   plane = d>>5, base[plane*NN*32 + n*32 + (d&31)]
// so each (plane, node) is one contiguous 64 B cache line.

// ---------------- W prep + cursor zeroing (once, tiny) ----------------
__global__ __launch_bounds__(256) void w_prep(const float* __restrict__ W1,
                                              const float* __restrict__ W2,
                                              ushort* __restrict__ W1t,
                                              ushort* __restrict__ W2t,
                                              int* __restrict__ cursorD,
                                              int* __restrict__ cursorS) {
  int b = blockIdx.x;                         // 0..127
  if (b == 0) cursorD[threadIdx.x] = 0;       // COARSE == 256 == blockDim
  if (b == 1) cursorS[threadIdx.x] = 0;
  const float* W = (b < 64) ? W1 : W2;
  ushort* Wt = (b < 64) ? W1t : W2t;
  int idx = (b & 63) * 256 + threadIdx.x;     // 0..16383
  int k = idx >> 7, n = idx & 127;
  Wt[n * F + k] = f2bf(W[idx]);
}

// ---------------- single-pass slotted binning (block-level cursors) ----------------
__global__ __launch_bounds__(256) void bin_edges(
    const int* __restrict__ src, const int* __restrict__ dst,
    const float* __restrict__ ew, int E,
    int* __restrict__ cursorD, int* __restrict__ cursorS,
    uint2* __restrict__ slotD, uchar* __restrict__ srcF) {
  __shared__ int cnt[4][COARSE];
  __shared__ int base[COARSE];
  bool isD = blockIdx.x < NBA;
  int blk = isD ? blockIdx.x : blockIdx.x - NBA;
  int nblk = isD ? NBA : NBS;
  const int* key = isD ? dst : src;
  int* cursor = isD ? cursorD : cursorS;
  int wave = threadIdx.x >> 6;
  for (int i = threadIdx.x; i < 4 * COARSE; i += 256) ((int*)cnt)[i] = 0;
  __syncthreads();
  int chunk = (E + nblk - 1) / nblk;
  int s0 = blk * chunk, s1 = min(E, s0 + chunk);
  for (int i = s0 + threadIdx.x; i < s1; i += 256)
    atomicAdd(&cnt[wave][key[i] >> 8], 1);
  __syncthreads();
  if (threadIdx.x < COARSE) {
    int b = threadIdx.x;
    int tot = cnt[0][b] + cnt[1][b] + cnt[2][b] + cnt[3][b];
    base[b] = tot ? atomicAdd(&cursor[b], tot) : 0;
    cnt[0][b] = 0;  // reuse row 0 as block-level scatter cursor
  }
  __syncthreads();
  if (isD) {
    for (int i = s0 + threadIdx.x; i < s1; i += 256) {
      int d = dst[i];
      int bin = d >> 8;
      int p = base[bin] + atomicAdd(&cnt[0][bin], 1);
      if (p < CAP_BIN) {
        uint2 v;
        v.x = (uint)(src[i] & 0xffff) | ((uint)f2bf(ew[i]) << 16);
        v.y = (uint)(d & 255);
        slotD[(size_t)bin * CAP_BIN + p] = v;
      }
    }
  } else {
    for (int i = s0 + threadIdx.x; i < s1; i += 256) {
      int s = src[i];
      int bin = s >> 8;
      int p = base[bin] + atomicAdd(&cnt[0][bin], 1);
      if (p < CAP_BIN) srcF[(size_t)bin * CAP_BIN + p] = (uchar)(s & 255);
    }
  }
}

// ---------------- per-bucket fine sort -> 4-aligned CSR rows ----------------
// Pad slots = 0x80000000 (src 0, bf16 -0.0): EW pass masks pads for free,
// non-EW masks via the sign bit.
__global__ __launch_bounds__(1024) void bucket_csr(
    const uint2* __restrict__ slotD, const int* __restrict__ cursorD,
    int2* __restrict__ rowRange, float* __restrict__ inNorm, uint* __restrict__ csr,
    const uchar* __restrict__ srcF, const int* __restrict__ cursorS,
    float* __restrict__ outNorm) {
  __shared__ int hist[256], base[256], cur[256];
  int t = threadIdx.x;
  if (blockIdx.x >= COARSE) {   // ---- S phase: outNorm ----
    int b = blockIdx.x - COARSE;
    int lo = b * CAP_BIN;
    int cntS = min(cursorS[b], CAP_BIN);
    if (t < 256) hist[t] = 0;
    __syncthreads();
    for (int i = lo + t; i < lo + cntS; i += 1024)
      atomicAdd(&hist[srcF[i]], 1);
    __syncthreads();
    if (t < 256) outNorm[b * 256 + t] = rsqrtf((float)max(hist[t], 1));
    return;
  }
  // ---- D phase ----
  int b = blockIdx.x;
  int lo = b * CAP_BIN;
  int cntD = min(cursorD[b], CAP_BIN);
  int hi = lo + cntD;
  if (t < 256) hist[t] = 0;
  __syncthreads();
  for (int i = lo + t; i < hi; i += 1024)
    atomicAdd(&hist[slotD[i].y], 1);
  __syncthreads();
  if (t < 256) base[t] = (hist[t] + 3) & ~3;
  __syncthreads();
  for (int off = 1; off < 256; off <<= 1) {
    int x = 0;
    if (t < 256 && t >= off) x = base[t - off];
    __syncthreads();
    if (t < 256) base[t] += x;
    __syncthreads();
  }
  if (t < 256) {
    int v = hist[t];
    int sz4 = (v + 3) & ~3;
    int st = b * CAP_CSR + base[t] - sz4;
    base[t] = st;
    cur[t] = 0;
    int node = b * 256 + t;
    rowRange[node] = make_int2(st, v);
    inNorm[node] = rsqrtf((float)max(v, 1));
    for (int p = st + v; p < st + sz4; ++p) csr[p] = 0x80000000u;  // pads
  }
  __syncthreads();
  for (int i = lo + t; i < hi; i += 1024) {
    uint2 v = slotD[i];
    int fine = v.y;
    int p = base[fine] + atomicAdd(&cur[fine], 1);
    csr[p] = v.x;
  }
}

// ---------------- MFMA GEMM (planar bf16 in/out) ----------------
template <bool BF16IN>
__global__ __launch_bounds__(256) void gemm_mfma(
    const void* __restrict__ Xv, const float* __restrict__ scale,
    const ushort* __restrict__ Wt, ushort* __restrict__ Y) {
  __shared__ ushort sA[128 * 136];
  __shared__ ushort sB[128 * 136];
  int t = threadIdx.x;
  int row0 = blockIdx.x * 128;

  {  // stage A
    int r = t >> 1, hf = t & 1;
    ushort* ap = sA + r * 136 + hf * 64;
    if (BF16IN) {
      const ushort* xp = (const ushort*)Xv;
#pragma unroll
      for (int j = 0; j < 8; ++j) {
        int q = 2 * hf + (j >> 2);   // plane of dim hf*64 + j*8
        *(ushort8*)(ap + j * 8) =
            *(const ushort8*)(xp + ((size_t)q * NN + row0 + r) * 32 + (j & 3) * 8);
      }
    } else {
      const float* xp = (const float*)Xv + (size_t)(row0 + r) * F + hf * 64;
      float s = scale[row0 + r];
#pragma unroll
      for (int j = 0; j < 8; ++j) {
        float4 v0 = *(const float4*)(xp + j * 8);
        float4 v1 = *(const float4*)(xp + j * 8 + 4);
        ushort8 o;
        o[0] = f2bf(v0.x * s); o[1] = f2bf(v0.y * s); o[2] = f2bf(v0.z * s); o[3] = f2bf(v0.w * s);
        o[4] = f2bf(v1.x * s); o[5] = f2bf(v1.y * s); o[6] = f2bf(v1.z * s); o[7] = f2bf(v1.w * s);
        *(ushort8*)(ap + j * 8) = o;
      }
    }
  }
  {  // stage B
    int n = t >> 1, hf = t & 1;
    const ushort* wp = Wt + n * F + hf * 64;
    ushort* bp = sB + n * 136 + hf * 64;
#pragma unroll
    for (int j = 0; j < 8; ++j)
      *(ushort8*)(bp + j * 8) = *(const ushort8*)(wp + j * 8);
  }
  __syncthreads();

  int lane = t & 63, wave = t >> 6;
  int quad = lane >> 4, l16 = lane & 15;
  int mrow0 = wave * 32;

  floatx4 acc[2][8];
#pragma unroll
  for (int a = 0; a < 2; ++a)
#pragma unroll
    for (int c = 0; c < 8; ++c) acc[a][c] = (floatx4){0.f, 0.f, 0.f, 0.f};

#pragma unroll
  for (int kc = 0; kc < 128; kc += 32) {
    short8 afrag[2], bfrag[8];
#pragma unroll
    for (int a = 0; a < 2; ++a)
      afrag[a] = *(const short8*)(sA + (mrow0 + a * 16 + l16) * 136 + kc + quad * 8);
#pragma unroll
    for (int c = 0; c < 8; ++c)
      bfrag[c] = *(const short8*)(sB + (c * 16 + l16) * 136 + kc + quad * 8);
#pragma unroll
    for (int a = 0; a < 2; ++a)
#pragma unroll
      for (int c = 0; c < 8; ++c)
        acc[a][c] = __builtin_amdgcn_mfma_f32_16x16x32_bf16(afrag[a], bfrag[c], acc[a][c], 0, 0, 0);
  }

#pragma unroll
  for (int a = 0; a < 2; ++a)
#pragma unroll
    for (int c = 0; c < 8; ++c)
#pragma unroll
      for (int r = 0; r < 4; ++r) {
        int row = row0 + mrow0 + a * 16 + quad * 4 + r;
        int col = c * 16 + l16;
        Y[((size_t)(col >> 5) * NN + row) * 32 + (col & 31)] = f2bf(acc[a][c][r]);
      }
}

// ---------------- SpMM v14: plane-PAIR blocks, csr re-read halved ----------------
// R7 flat structure + csr prefetch, re-indexed: wave = 8 groups x 8 lanes.
// Group owns 1 node and a plane PAIR; lane j: plane = pair*2 + (j>>2),
// 16 B slot = j&3. One gather wave-instr still = 16 x 64 B segments
// (8 groups x 2 planes); loads in flight, edge order, and numerics are
// identical to R7. Each csr row is now streamed by 2 blocks instead of 4:
// csr+rowRange re-read traffic halves (~9 MB/stage).
// Grid: 2 pairs x N/32 chunks = N/16 blocks (unchanged).

template <bool EW, bool NB, bool RELU, bool PS, bool OUT_BF16>
__global__ __launch_bounds__(256) void spmm(
    const ushort* __restrict__ hb, const int2* __restrict__ rowRange,
    const uint* __restrict__ csr, const float* __restrict__ inNorm,
    const float* __restrict__ bias, const float* __restrict__ postScale,
    void* __restrict__ outv) {
  int bid = blockIdx.x;
  int pair = bid & 1;             // plane pair 0 (planes 0,1) / 1 (planes 2,3)
  int chunk = bid >> 1;           // 32-node chunk
  int lane = threadIdx.x & 63;
  int g = lane >> 3;              // node group 0..7
  int j = lane & 7;               // lane within group
  int plane = pair * 2 + (j >> 2);
  int js = j & 3;                 // 16 B slot within the 64 B plane row
  int n = chunk * 32 + (threadIdx.x >> 6) * 8 + g;
  int2 r = rowRange[n];
  int len4 = (r.y + 3) & ~3;
  const char* pb = (const char*)hb + (size_t)plane * ((size_t)NN * 64);
  uint joff = (uint)js << 4;
  float acc[8] = {0.f, 0.f, 0.f, 0.f, 0.f, 0.f, 0.f, 0.f};

#define GQ(e, c, q_)                                                     \
  {                                                                      \
    uint ei = (e);                                                       \
    c = *(const uint4*)(pb + (((ei & 0xffffu) << 6) | joff));            \
    q_ = EW ? __uint_as_float(ei & 0xffff0000u)                          \
            : ((int)ei >= 0 ? 1.0f : 0.0f);                              \
  }
#define ACC8(c, q_)                                                     \
  {                                                                     \
    acc[0] = fmaf(__uint_as_float(c.x << 16), q_, acc[0]);              \
    acc[1] = fmaf(__uint_as_float(c.x & 0xffff0000u), q_, acc[1]);      \
    acc[2] = fmaf(__uint_as_float(c.y << 16), q_, acc[2]);              \
    acc[3] = fmaf(__uint_as_float(c.y & 0xffff0000u), q_, acc[3]);      \
    acc[4] = fmaf(__uint_as_float(c.z << 16), q_, acc[4]);              \
    acc[5] = fmaf(__uint_as_float(c.z & 0xffff0000u), q_, acc[5]);      \
    acc[6] = fmaf(__uint_as_float(c.w << 16), q_, acc[6]);              \
    acc[7] = fmaf(__uint_as_float(c.w & 0xffff0000u), q_, acc[7]);      \
  }

  int i = 0;
  uint4 e0, e1;
  if (i + 8 <= len4) {
    e0 = *(const uint4*)(csr + r.x);
    e1 = *(const uint4*)(csr + r.x + 4);
  }
  while (i + 8 <= len4) {           // 8 edges: 8 gathers; next csr prefetched
    uint4 c0, c1, c2, c3, c4, c5, c6, c7;
    float q0, q1, q2, q3, q4, q5, q6, q7;
    GQ(e0.x, c0, q0) GQ(e0.y, c1, q1) GQ(e0.z, c2, q2) GQ(e0.w, c3, q3)
    GQ(e1.x, c4, q4) GQ(e1.y, c5, q5) GQ(e1.z, c6, q6) GQ(e1.w, c7, q7)
    uint4 f0, f1;
    bool more = (i + 16 <= len4);
    if (more) {
      f0 = *(const uint4*)(csr + r.x + i + 8);
      f1 = *(const uint4*)(csr + r.x + i + 12);
    }
    ACC8(c0, q0) ACC8(c1, q1) ACC8(c2, q2) ACC8(c3, q3)
    ACC8(c4, q4) ACC8(c5, q5) ACC8(c6, q6) ACC8(c7, q7)
    if (more) { e0 = f0; e1 = f1; }
    i += 8;
  }
  if (i < len4) {                         // 4 edges
    uint4 t0 = *(const uint4*)(csr + r.x + i);
    uint4 c0, c1, c2, c3;
    float q0, q1, q2, q3;
    GQ(t0.x, c0, q0) GQ(t0.y, c1, q1) GQ(t0.z, c2, q2) GQ(t0.w, c3, q3)
    ACC8(c0, q0) ACC8(c1, q1) ACC8(c2, q2) ACC8(c3, q3)
  }
#undef GQ
#undef ACC8

  if (NB) {
    float sc = inNorm[n];
    float4 b0 = ((const float4*)bias)[plane * 8 + js * 2];
    float4 b1 = ((const float4*)bias)[plane * 8 + js * 2 + 1];
    float bb[8] = {b0.x, b0.y, b0.z, b0.w, b1.x, b1.y, b1.z, b1.w};
#pragma unroll
    for (int k = 0; k < 8; ++k) {
      acc[k] = fmaf(acc[k], sc, bb[k]);
      if (RELU) acc[k] = fmaxf(acc[k], 0.f);
    }
    if (PS) {
      float o = postScale[n];
#pragma unroll
      for (int k = 0; k < 8; ++k) acc[k] *= o;
    }
  }
  if (OUT_BF16) {   // planar bf16: lane writes 16 B of its plane's 64 B row
    uint4 o;
    o.x = ((uint)f2bf(acc[1]) << 16) | (uint)f2bf(acc[0]);
    o.y = ((uint)f2bf(acc[3]) << 16) | (uint)f2bf(acc[2]);
    o.z = ((uint)f2bf(acc[5]) << 16) | (uint)f2bf(acc[4]);
    o.w = ((uint)f2bf(acc[7]) << 16) | (uint)f2bf(acc[6]);
    ((uint4*)outv)[((size_t)plane * NN + n) * 4 + js] = o;
  } else {          // fp32 row-major final output
    float4 lo = {acc[0], acc[1], acc[2], acc[3]};
    float4 hi = {acc[4], acc[5], acc[6], acc[7]};
    ((float4*)outv)[(size_t)n * 32 + plane * 8 + js * 2] = lo;
    ((float4*)outv)[(size_t)n * 32 + plane * 8 + js * 2 + 1] = hi;
  }
}

// ---------------- launch ----------------

extern "C" void kernel_launch(void* const* d_in, const int* in_sizes, int n_in,
                              void* d_out, int out_size, void* d_ws, size_t ws_size,
                              hipStream_t stream) {
  const float* feat = (const float*)d_in[0];
  const float* ew   = (const float*)d_in[1];
  const float* W1   = (const float*)d_in[2];
  const float* b1   = (const float*)d_in[3];
  const float* W2   = (const float*)d_in[4];
  const float* b2   = (const float*)d_in[5];
  const int*   src  = (const int*)d_in[6];
  const int*   dst  = (const int*)d_in[7];
  const int N = in_sizes[0] / F;   // 65536
  const int E = in_sizes[6];
  float* out = (float*)d_out;

  char* ws = (char*)d_ws;
  size_t off = 0;
  auto alloc = [&](size_t bytes) {
    void* p = ws + off;
    off += (bytes + 255) & ~(size_t)255;
    return p;
  };
  int2*   rowRange = (int2*)alloc((size_t)N * 8);
  float*  inNorm   = (float*)alloc((size_t)N * 4);
  float*  outNorm  = (float*)alloc((size_t)N * 4);
  ushort* W1t      = (ushort*)alloc((size_t)F * F * 2);
  ushort* W2t      = (ushort*)alloc((size_t)F * F * 2);
  int*    cursorD  = (int*)alloc(COARSE * 4);
  int*    cursorS  = (int*)alloc(COARSE * 4);
  uint*   csr      = (uint*)alloc((size_t)COARSE * CAP_CSR * 4);
  ushort* bufAb    = (ushort*)alloc((size_t)N * F * 2);
  ushort* bufBb    = (ushort*)alloc((size_t)N * F * 2);
  ushort* bufCb    = (ushort*)alloc((size_t)N * F * 2);
  if (off > ws_size) return;

  uint2* slotD;
  uchar* srcF;
  {
    char* tp = (char*)bufBb;
    size_t toff = 0;
    auto talloc = [&](size_t bytes) {
      void* p = tp + toff;
      toff += (bytes + 255) & ~(size_t)255;
      return p;
    };
    slotD = (uint2*)talloc((size_t)COARSE * CAP_BIN * 8);
    srcF  = (uchar*)talloc((size_t)COARSE * CAP_BIN);
  }

  w_prep<<<128, 256, 0, stream>>>(W1, W2, W1t, W2t, cursorD, cursorS);
  bin_edges<<<NBA + NBS, 256, 0, stream>>>(src, dst, ew, E, cursorD, cursorS, slotD, srcF);
  bucket_csr<<<2 * COARSE, 1024, 0, stream>>>(slotD, cursorD, rowRange, inNorm, csr,
                                              srcF, cursorS, outNorm);

  // layer 1: h1pre = bf16( relu(SpMM(bf16((feat*outNorm)@W1)) * inNorm + b1) * outNorm )
  gemm_mfma<false><<<N / 128, 256, 0, stream>>>(feat, outNorm, W1t, bufAb);
  spmm<false, true, true, true, true><<<N / 16, 256, 0, stream>>>(
      bufAb, rowRange, csr, inNorm, b1, outNorm, bufBb);
  // layer 2: h2 = bf16( SpMM(bf16(h1pre@W2)) * inNorm + b2 )
  gemm_mfma<true><<<N / 128, 256, 0, stream>>>(bufBb, nullptr, W2t, bufAb);
  spmm<false, true, false, false, true><<<N / 16, 256, 0, stream>>>(
      bufAb, rowRange, csr, inNorm, b2, nullptr, bufCb);
  // final: out = segment_sum(h2[src] * eweight, dst)   [fp32 out]
  spmm<true, false, false, false, false><<<N / 16, 256, 0, stream>>>(
      bufCb, rowRange, csr, nullptr, nullptr, nullptr, out);
}

// Round 10
// 258.929 us; speedup vs baseline: 1.1893x; 1.1893x over previous
//
#include <hip/hip_runtime.h>

#define F 128
#define NN 65536       // node count (layout assumes this, as does COARSE)
#define NBA 512        // D-side binning blocks
#define NBS 128        // S-side binning blocks
#define COARSE 256     // coarse buckets = node >> 8  (assumes N = 65536)
#define CAP_BIN 4864   // slot capacity per bucket, pre-sort (mean 4096, 12 sigma)
#define CAP_CSR 5632   // slot capacity per bucket, post-sort w/ per-row 4-align pads

typedef unsigned int uint;
typedef unsigned short ushort;
typedef unsigned char uchar;
typedef __attribute__((ext_vector_type(8))) short short8;
typedef __attribute__((ext_vector_type(8))) unsigned short ushort8;
typedef __attribute__((ext_vector_type(4))) float floatx4;

__device__ __forceinline__ ushort f2bf(float f) {
  uint u = __float_as_uint(f);
  u += 0x7fffu + ((u >> 16) & 1u);   // round-to-nearest-even
  return (ushort)(u >> 16);
}

// Planar bf16 table layout: element (node n, dim d) lives at
//   plane = d>>5, base[plane*NN*32 + n*32 + (d&31)]
// so each (plane, node) is one contiguous 64 B cache line.

// ---------------- W prep + cursor zeroing (once, tiny) ----------------
__global__ __launch_bounds__(256) void w_prep(const float* __restrict__ W1,
                                              const float* __restrict__ W2,
                                              ushort* __restrict__ W1t,
                                              ushort* __restrict__ W2t,
                                              int* __restrict__ cursorD,
                                              int* __restrict__ cursorS) {
  int b = blockIdx.x;                         // 0..127
  if (b == 0) cursorD[threadIdx.x] = 0;       // COARSE == 256 == blockDim
  if (b == 1) cursorS[threadIdx.x] = 0;
  const float* W = (b < 64) ? W1 : W2;
  ushort* Wt = (b < 64) ? W1t : W2t;
  int idx = (b & 63) * 256 + threadIdx.x;     // 0..16383
  int k = idx >> 7, n = idx & 127;
  Wt[n * F + k] = f2bf(W[idx]);
}

// ---------------- single-pass slotted binning (block-level cursors) ----------------
__global__ __launch_bounds__(256) void bin_edges(
    const int* __restrict__ src, const int* __restrict__ dst,
    const float* __restrict__ ew, int E,
    int* __restrict__ cursorD, int* __restrict__ cursorS,
    uint2* __restrict__ slotD, uchar* __restrict__ srcF) {
  __shared__ int cnt[4][COARSE];
  __shared__ int base[COARSE];
  bool isD = blockIdx.x < NBA;
  int blk = isD ? blockIdx.x : blockIdx.x - NBA;
  int nblk = isD ? NBA : NBS;
  const int* key = isD ? dst : src;
  int* cursor = isD ? cursorD : cursorS;
  int wave = threadIdx.x >> 6;
  for (int i = threadIdx.x; i < 4 * COARSE; i += 256) ((int*)cnt)[i] = 0;
  __syncthreads();
  int chunk = (E + nblk - 1) / nblk;
  int s0 = blk * chunk, s1 = min(E, s0 + chunk);
  for (int i = s0 + threadIdx.x; i < s1; i += 256)
    atomicAdd(&cnt[wave][key[i] >> 8], 1);
  __syncthreads();
  if (threadIdx.x < COARSE) {
    int b = threadIdx.x;
    int tot = cnt[0][b] + cnt[1][b] + cnt[2][b] + cnt[3][b];
    base[b] = tot ? atomicAdd(&cursor[b], tot) : 0;
    cnt[0][b] = 0;  // reuse row 0 as block-level scatter cursor
  }
  __syncthreads();
  if (isD) {
    for (int i = s0 + threadIdx.x; i < s1; i += 256) {
      int d = dst[i];
      int bin = d >> 8;
      int p = base[bin] + atomicAdd(&cnt[0][bin], 1);
      if (p < CAP_BIN) {
        uint2 v;
        v.x = (uint)(src[i] & 0xffff) | ((uint)f2bf(ew[i]) << 16);
        v.y = (uint)(d & 255);
        slotD[(size_t)bin * CAP_BIN + p] = v;
      }
    }
  } else {
    for (int i = s0 + threadIdx.x; i < s1; i += 256) {
      int s = src[i];
      int bin = s >> 8;
      int p = base[bin] + atomicAdd(&cnt[0][bin], 1);
      if (p < CAP_BIN) srcF[(size_t)bin * CAP_BIN + p] = (uchar)(s & 255);
    }
  }
}

// ---------------- per-bucket fine sort -> 4-aligned CSR rows ----------------
// Pad slots = 0x80000000 (src 0, bf16 -0.0): EW pass masks pads for free,
// non-EW masks via the sign bit.
__global__ __launch_bounds__(1024) void bucket_csr(
    const uint2* __restrict__ slotD, const int* __restrict__ cursorD,
    int2* __restrict__ rowRange, float* __restrict__ inNorm, uint* __restrict__ csr,
    const uchar* __restrict__ srcF, const int* __restrict__ cursorS,
    float* __restrict__ outNorm) {
  __shared__ int hist[256], base[256], cur[256];
  int t = threadIdx.x;
  if (blockIdx.x >= COARSE) {   // ---- S phase: outNorm ----
    int b = blockIdx.x - COARSE;
    int lo = b * CAP_BIN;
    int cntS = min(cursorS[b], CAP_BIN);
    if (t < 256) hist[t] = 0;
    __syncthreads();
    for (int i = lo + t; i < lo + cntS; i += 1024)
      atomicAdd(&hist[srcF[i]], 1);
    __syncthreads();
    if (t < 256) outNorm[b * 256 + t] = rsqrtf((float)max(hist[t], 1));
    return;
  }
  // ---- D phase ----
  int b = blockIdx.x;
  int lo = b * CAP_BIN;
  int cntD = min(cursorD[b], CAP_BIN);
  int hi = lo + cntD;
  if (t < 256) hist[t] = 0;
  __syncthreads();
  for (int i = lo + t; i < hi; i += 1024)
    atomicAdd(&hist[slotD[i].y], 1);
  __syncthreads();
  if (t < 256) base[t] = (hist[t] + 3) & ~3;
  __syncthreads();
  for (int off = 1; off < 256; off <<= 1) {
    int x = 0;
    if (t < 256 && t >= off) x = base[t - off];
    __syncthreads();
    if (t < 256) base[t] += x;
    __syncthreads();
  }
  if (t < 256) {
    int v = hist[t];
    int sz4 = (v + 3) & ~3;
    int st = b * CAP_CSR + base[t] - sz4;
    base[t] = st;
    cur[t] = 0;
    int node = b * 256 + t;
    rowRange[node] = make_int2(st, v);
    inNorm[node] = rsqrtf((float)max(v, 1));
    for (int p = st + v; p < st + sz4; ++p) csr[p] = 0x80000000u;  // pads
  }
  __syncthreads();
  for (int i = lo + t; i < hi; i += 1024) {
    uint2 v = slotD[i];
    int fine = v.y;
    int p = base[fine] + atomicAdd(&cur[fine], 1);
    csr[p] = v.x;
  }
}

// ---------------- MFMA GEMM (planar bf16 in/out) ----------------
template <bool BF16IN>
__global__ __launch_bounds__(256) void gemm_mfma(
    const void* __restrict__ Xv, const float* __restrict__ scale,
    const ushort* __restrict__ Wt, ushort* __restrict__ Y) {
  __shared__ ushort sA[128 * 136];
  __shared__ ushort sB[128 * 136];
  int t = threadIdx.x;
  int row0 = blockIdx.x * 128;

  {  // stage A
    int r = t >> 1, hf = t & 1;
    ushort* ap = sA + r * 136 + hf * 64;
    if (BF16IN) {
      const ushort* xp = (const ushort*)Xv;
#pragma unroll
      for (int j = 0; j < 8; ++j) {
        int q = 2 * hf + (j >> 2);   // plane of dim hf*64 + j*8
        *(ushort8*)(ap + j * 8) =
            *(const ushort8*)(xp + ((size_t)q * NN + row0 + r) * 32 + (j & 3) * 8);
      }
    } else {
      const float* xp = (const float*)Xv + (size_t)(row0 + r) * F + hf * 64;
      float s = scale[row0 + r];
#pragma unroll
      for (int j = 0; j < 8; ++j) {
        float4 v0 = *(const float4*)(xp + j * 8);
        float4 v1 = *(const float4*)(xp + j * 8 + 4);
        ushort8 o;
        o[0] = f2bf(v0.x * s); o[1] = f2bf(v0.y * s); o[2] = f2bf(v0.z * s); o[3] = f2bf(v0.w * s);
        o[4] = f2bf(v1.x * s); o[5] = f2bf(v1.y * s); o[6] = f2bf(v1.z * s); o[7] = f2bf(v1.w * s);
        *(ushort8*)(ap + j * 8) = o;
      }
    }
  }
  {  // stage B
    int n = t >> 1, hf = t & 1;
    const ushort* wp = Wt + n * F + hf * 64;
    ushort* bp = sB + n * 136 + hf * 64;
#pragma unroll
    for (int j = 0; j < 8; ++j)
      *(ushort8*)(bp + j * 8) = *(const ushort8*)(wp + j * 8);
  }
  __syncthreads();

  int lane = t & 63, wave = t >> 6;
  int quad = lane >> 4, l16 = lane & 15;
  int mrow0 = wave * 32;

  floatx4 acc[2][8];
#pragma unroll
  for (int a = 0; a < 2; ++a)
#pragma unroll
    for (int c = 0; c < 8; ++c) acc[a][c] = (floatx4){0.f, 0.f, 0.f, 0.f};

#pragma unroll
  for (int kc = 0; kc < 128; kc += 32) {
    short8 afrag[2], bfrag[8];
#pragma unroll
    for (int a = 0; a < 2; ++a)
      afrag[a] = *(const short8*)(sA + (mrow0 + a * 16 + l16) * 136 + kc + quad * 8);
#pragma unroll
    for (int c = 0; c < 8; ++c)
      bfrag[c] = *(const short8*)(sB + (c * 16 + l16) * 136 + kc + quad * 8);
#pragma unroll
    for (int a = 0; a < 2; ++a)
#pragma unroll
      for (int c = 0; c < 8; ++c)
        acc[a][c] = __builtin_amdgcn_mfma_f32_16x16x32_bf16(afrag[a], bfrag[c], acc[a][c], 0, 0, 0);
  }

#pragma unroll
  for (int a = 0; a < 2; ++a)
#pragma unroll
    for (int c = 0; c < 8; ++c)
#pragma unroll
      for (int r = 0; r < 4; ++r) {
        int row = row0 + mrow0 + a * 16 + quad * 4 + r;
        int col = c * 16 + l16;
        Y[((size_t)(col >> 5) * NN + row) * 32 + (col & 31)] = f2bf(acc[a][c][r]);
      }
}

// ---------------- SpMM v13: R3 flat structure + csr software prefetch ----------------
// The verified 259.2 us configuration: plane = (bid&7)>>1 interleave, one
// plane per block (4.2 MB instantaneous gather footprint -- L2 re-references
// survive; R8/R9 proved wider footprints lose 50-100 MB of FETCH), normal
// loads/stores (nt costs ~40%, R6), next iteration's csr loads issued before
// the current FMA chain. Wave = 16 groups x 4 lanes; group owns 1 node,
// lane j owns 16 B of the 64 B plane row. One gather wave-instr = 16 x 64 B.

template <bool EW, bool NB, bool RELU, bool PS, bool OUT_BF16>
__global__ __launch_bounds__(256) void spmm(
    const ushort* __restrict__ hb, const int2* __restrict__ rowRange,
    const uint* __restrict__ csr, const float* __restrict__ inNorm,
    const float* __restrict__ bias, const float* __restrict__ postScale,
    void* __restrict__ outv) {
  int bid = blockIdx.x;
  int plane = (bid & 7) >> 1;
  int chunk = ((bid >> 3) << 1) | (bid & 1);
  int lane = threadIdx.x & 63;
  int g = lane >> 2;        // node group 0..15
  int j = lane & 3;         // 16 B slot within the 64 B plane row
  int n = chunk * 64 + (threadIdx.x >> 6) * 16 + g;
  int2 r = rowRange[n];
  int len4 = (r.y + 3) & ~3;
  const char* pb = (const char*)hb + (size_t)plane * ((size_t)NN * 64);
  uint joff = (uint)j << 4;
  float acc[8] = {0.f, 0.f, 0.f, 0.f, 0.f, 0.f, 0.f, 0.f};

#define GQ(e, c, q_)                                                     \
  {                                                                      \
    uint ei = (e);                                                       \
    c = *(const uint4*)(pb + (((ei & 0xffffu) << 6) | joff));            \
    q_ = EW ? __uint_as_float(ei & 0xffff0000u)                          \
            : ((int)ei >= 0 ? 1.0f : 0.0f);                              \
  }
#define ACC8(c, q_)                                                     \
  {                                                                     \
    acc[0] = fmaf(__uint_as_float(c.x << 16), q_, acc[0]);              \
    acc[1] = fmaf(__uint_as_float(c.x & 0xffff0000u), q_, acc[1]);      \
    acc[2] = fmaf(__uint_as_float(c.y << 16), q_, acc[2]);              \
    acc[3] = fmaf(__uint_as_float(c.y & 0xffff0000u), q_, acc[3]);      \
    acc[4] = fmaf(__uint_as_float(c.z << 16), q_, acc[4]);              \
    acc[5] = fmaf(__uint_as_float(c.z & 0xffff0000u), q_, acc[5]);      \
    acc[6] = fmaf(__uint_as_float(c.w << 16), q_, acc[6]);              \
    acc[7] = fmaf(__uint_as_float(c.w & 0xffff0000u), q_, acc[7]);      \
  }

  int i = 0;
  uint4 e0, e1;
  if (i + 8 <= len4) {
    e0 = *(const uint4*)(csr + r.x);
    e1 = *(const uint4*)(csr + r.x + 4);
  }
  while (i + 8 <= len4) {           // 8 edges: 8 gathers; next csr prefetched
    uint4 c0, c1, c2, c3, c4, c5, c6, c7;
    float q0, q1, q2, q3, q4, q5, q6, q7;
    GQ(e0.x, c0, q0) GQ(e0.y, c1, q1) GQ(e0.z, c2, q2) GQ(e0.w, c3, q3)
    GQ(e1.x, c4, q4) GQ(e1.y, c5, q5) GQ(e1.z, c6, q6) GQ(e1.w, c7, q7)
    uint4 f0, f1;
    bool more = (i + 16 <= len4);
    if (more) {
      f0 = *(const uint4*)(csr + r.x + i + 8);
      f1 = *(const uint4*)(csr + r.x + i + 12);
    }
    ACC8(c0, q0) ACC8(c1, q1) ACC8(c2, q2) ACC8(c3, q3)
    ACC8(c4, q4) ACC8(c5, q5) ACC8(c6, q6) ACC8(c7, q7)
    if (more) { e0 = f0; e1 = f1; }
    i += 8;
  }
  if (i < len4) {                         // 4 edges
    uint4 t0 = *(const uint4*)(csr + r.x + i);
    uint4 c0, c1, c2, c3;
    float q0, q1, q2, q3;
    GQ(t0.x, c0, q0) GQ(t0.y, c1, q1) GQ(t0.z, c2, q2) GQ(t0.w, c3, q3)
    ACC8(c0, q0) ACC8(c1, q1) ACC8(c2, q2) ACC8(c3, q3)
  }
#undef GQ
#undef ACC8

  if (NB) {
    float sc = inNorm[n];
    float4 b0 = ((const float4*)bias)[plane * 8 + j * 2];
    float4 b1 = ((const float4*)bias)[plane * 8 + j * 2 + 1];
    float bb[8] = {b0.x, b0.y, b0.z, b0.w, b1.x, b1.y, b1.z, b1.w};
#pragma unroll
    for (int k = 0; k < 8; ++k) {
      acc[k] = fmaf(acc[k], sc, bb[k]);
      if (RELU) acc[k] = fmaxf(acc[k], 0.f);
    }
    if (PS) {
      float o = postScale[n];
#pragma unroll
      for (int k = 0; k < 8; ++k) acc[k] *= o;
    }
  }
  if (OUT_BF16) {   // planar bf16: lane j writes 16 B of the 64 B plane row
    uint4 o;
    o.x = ((uint)f2bf(acc[1]) << 16) | (uint)f2bf(acc[0]);
    o.y = ((uint)f2bf(acc[3]) << 16) | (uint)f2bf(acc[2]);
    o.z = ((uint)f2bf(acc[5]) << 16) | (uint)f2bf(acc[4]);
    o.w = ((uint)f2bf(acc[7]) << 16) | (uint)f2bf(acc[6]);
    ((uint4*)outv)[((size_t)plane * NN + n) * 4 + j] = o;
  } else {          // fp32 row-major final output
    float4 lo = {acc[0], acc[1], acc[2], acc[3]};
    float4 hi = {acc[4], acc[5], acc[6], acc[7]};
    ((float4*)outv)[(size_t)n * 32 + plane * 8 + j * 2] = lo;
    ((float4*)outv)[(size_t)n * 32 + plane * 8 + j * 2 + 1] = hi;
  }
}

// ---------------- launch ----------------

extern "C" void kernel_launch(void* const* d_in, const int* in_sizes, int n_in,
                              void* d_out, int out_size, void* d_ws, size_t ws_size,
                              hipStream_t stream) {
  const float* feat = (const float*)d_in[0];
  const float* ew   = (const float*)d_in[1];
  const float* W1   = (const float*)d_in[2];
  const float* b1   = (const float*)d_in[3];
  const float* W2   = (const float*)d_in[4];
  const float* b2   = (const float*)d_in[5];
  const int*   src  = (const int*)d_in[6];
  const int*   dst  = (const int*)d_in[7];
  const int N = in_sizes[0] / F;   // 65536
  const int E = in_sizes[6];
  float* out = (float*)d_out;

  char* ws = (char*)d_ws;
  size_t off = 0;
  auto alloc = [&](size_t bytes) {
    void* p = ws + off;
    off += (bytes + 255) & ~(size_t)255;
    return p;
  };
  int2*   rowRange = (int2*)alloc((size_t)N * 8);
  float*  inNorm   = (float*)alloc((size_t)N * 4);
  float*  outNorm  = (float*)alloc((size_t)N * 4);
  ushort* W1t      = (ushort*)alloc((size_t)F * F * 2);
  ushort* W2t      = (ushort*)alloc((size_t)F * F * 2);
  int*    cursorD  = (int*)alloc(COARSE * 4);
  int*    cursorS  = (int*)alloc(COARSE * 4);
  uint*   csr      = (uint*)alloc((size_t)COARSE * CAP_CSR * 4);
  ushort* bufAb    = (ushort*)alloc((size_t)N * F * 2);
  ushort* bufBb    = (ushort*)alloc((size_t)N * F * 2);
  ushort* bufCb    = (ushort*)alloc((size_t)N * F * 2);
  if (off > ws_size) return;

  uint2* slotD;
  uchar* srcF;
  {
    char* tp = (char*)bufBb;
    size_t toff = 0;
    auto talloc = [&](size_t bytes) {
      void* p = tp + toff;
      toff += (bytes + 255) & ~(size_t)255;
      return p;
    };
    slotD = (uint2*)talloc((size_t)COARSE * CAP_BIN * 8);
    srcF  = (uchar*)talloc((size_t)COARSE * CAP_BIN);
  }

  w_prep<<<128, 256, 0, stream>>>(W1, W2, W1t, W2t, cursorD, cursorS);
  bin_edges<<<NBA + NBS, 256, 0, stream>>>(src, dst, ew, E, cursorD, cursorS, slotD, srcF);
  bucket_csr<<<2 * COARSE, 1024, 0, stream>>>(slotD, cursorD, rowRange, inNorm, csr,
                                              srcF, cursorS, outNorm);

  // layer 1: h1pre = bf16( relu(SpMM(bf16((feat*outNorm)@W1)) * inNorm + b1) * outNorm )
  gemm_mfma<false><<<N / 128, 256, 0, stream>>>(feat, outNorm, W1t, bufAb);
  spmm<false, true, true, true, true><<<N / 16, 256, 0, stream>>>(
      bufAb, rowRange, csr, inNorm, b1, outNorm, bufBb);
  // layer 2: h2 = bf16( SpMM(bf16(h1pre@W2)) * inNorm + b2 )
  gemm_mfma<true><<<N / 128, 256, 0, stream>>>(bufBb, nullptr, W2t, bufAb);
  spmm<false, true, false, false, true><<<N / 16, 256, 0, stream>>>(
      bufAb, rowRange, csr, inNorm, b2, nullptr, bufCb);
  // final: out = segment_sum(h2[src] * eweight, dst)   [fp32 out]
  spmm<true, false, false, false, false><<<N / 16, 256, 0, stream>>>(
      bufCb, rowRange, csr, nullptr, nullptr, nullptr, out);
}